// Round 1
// baseline (1995.677 us; speedup 1.0000x reference)
//
#include <hip/hip_runtime.h>
#include <hip/hip_bf16.h>

#define LRELU(x) ((x) > 0.0f ? (x) : 0.01f * (x))

// Monotonic float -> uint encoding: f1 > f2  <=>  enc(f1) > enc(f2).
// enc of any finite float is > 0x007FFFFF, so 0 is a safe "empty" sentinel.
__device__ __forceinline__ unsigned fenc(float f) {
    unsigned u = __float_as_uint(f);
    return (u & 0x80000000u) ? ~u : (u | 0x80000000u);
}
__device__ __forceinline__ float fdec(unsigned u) {
    return (u & 0x80000000u) ? __uint_as_float(u & 0x7fffffffu) : __uint_as_float(~u);
}

// ---------------------------------------------------------------------------
// Node embedding MLP: h = L3(relu(L2(relu(L1(x)))))   x:[N,4] -> h:[N,64]
// Weight-stationary: lane = output channel; W2/W3 columns live in VGPRs.
// Cross-lane activation broadcast via per-wave LDS row (uniform-addr reads).
// ---------------------------------------------------------------------------
__global__ __launch_bounds__(256) void node_mlp_kernel(
    const float* __restrict__ x,
    const float* __restrict__ W1, const float* __restrict__ b1,
    const float* __restrict__ W2, const float* __restrict__ b2,
    const float* __restrict__ W3, const float* __restrict__ b3,
    float* __restrict__ h, int N)
{
    __shared__ __align__(16) float smem[4 * 64];
    const int lane = threadIdx.x & 63;
    const int wid  = threadIdx.x >> 6;

    float w1c[4], w2c[64], w3c[64];
#pragma unroll
    for (int i = 0; i < 4; ++i)  w1c[i] = W1[i * 64 + lane];
#pragma unroll
    for (int k = 0; k < 64; ++k) w2c[k] = W2[k * 64 + lane];
#pragma unroll
    for (int k = 0; k < 64; ++k) w3c[k] = W3[k * 64 + lane];
    const float bb1 = b1[lane], bb2 = b2[lane], bb3 = b3[lane];

    const int nwave = gridDim.x * 4;
    const int w     = blockIdx.x * 4 + wid;
    const int chunk = (N + nwave - 1) / nwave;
    const int n0 = w * chunk;
    const int n1 = min(N, n0 + chunk);
    float* myrow = &smem[wid * 64];

    for (int n = n0; n < n1; ++n) {
        const float4 xv = *reinterpret_cast<const float4*>(x + (size_t)n * 4);
        float a1 = bb1 + xv.x * w1c[0] + xv.y * w1c[1] + xv.z * w1c[2] + xv.w * w1c[3];
        a1 = fmaxf(a1, 0.0f);
        myrow[lane] = a1;
        asm volatile("s_waitcnt lgkmcnt(0)" ::: "memory");
        float a2 = bb2;
#pragma unroll
        for (int k4 = 0; k4 < 16; ++k4) {
            const float4 hv = *reinterpret_cast<const float4*>(&myrow[k4 * 4]);
            a2 += hv.x * w2c[k4 * 4] + hv.y * w2c[k4 * 4 + 1] +
                  hv.z * w2c[k4 * 4 + 2] + hv.w * w2c[k4 * 4 + 3];
        }
        a2 = fmaxf(a2, 0.0f);
        asm volatile("s_waitcnt lgkmcnt(0)" ::: "memory");
        myrow[lane] = a2;
        asm volatile("s_waitcnt lgkmcnt(0)" ::: "memory");
        float a3 = bb3;
#pragma unroll
        for (int k4 = 0; k4 < 16; ++k4) {
            const float4 hv = *reinterpret_cast<const float4*>(&myrow[k4 * 4]);
            a3 += hv.x * w3c[k4 * 4] + hv.y * w3c[k4 * 4 + 1] +
                  hv.z * w3c[k4 * 4 + 2] + hv.w * w3c[k4 * 4 + 3];
        }
        h[(size_t)n * 64 + lane] = a3;
    }
}

// ---------------------------------------------------------------------------
// Edge embedding MLP: ea_out(bf16) = L3(relu(L2(relu(L1(edge_attr)))))
// edge_attr:[E,8] -> ea:[E,64] stored bf16 (halves HBM traffic; tol is 1e-2)
// ---------------------------------------------------------------------------
__global__ __launch_bounds__(256) void edge_mlp_kernel(
    const float* __restrict__ eattr,
    const float* __restrict__ W1, const float* __restrict__ b1,
    const float* __restrict__ W2, const float* __restrict__ b2,
    const float* __restrict__ W3, const float* __restrict__ b3,
    __hip_bfloat16* __restrict__ eout, int E)
{
    __shared__ __align__(16) float smem[4 * 64];
    const int lane = threadIdx.x & 63;
    const int wid  = threadIdx.x >> 6;

    float w1c[8], w2c[64], w3c[64];
#pragma unroll
    for (int i = 0; i < 8; ++i)  w1c[i] = W1[i * 64 + lane];
#pragma unroll
    for (int k = 0; k < 64; ++k) w2c[k] = W2[k * 64 + lane];
#pragma unroll
    for (int k = 0; k < 64; ++k) w3c[k] = W3[k * 64 + lane];
    const float bb1 = b1[lane], bb2 = b2[lane], bb3 = b3[lane];

    const int nwave = gridDim.x * 4;
    const int w     = blockIdx.x * 4 + wid;
    const int chunk = (E + nwave - 1) / nwave;
    const int e0 = w * chunk;
    const int e1 = min(E, e0 + chunk);
    float* myrow = &smem[wid * 64];

    for (int e = e0; e < e1; ++e) {
        const float4 av0 = *reinterpret_cast<const float4*>(eattr + (size_t)e * 8);
        const float4 av1 = *reinterpret_cast<const float4*>(eattr + (size_t)e * 8 + 4);
        float a1 = bb1 + av0.x * w1c[0] + av0.y * w1c[1] + av0.z * w1c[2] + av0.w * w1c[3]
                       + av1.x * w1c[4] + av1.y * w1c[5] + av1.z * w1c[6] + av1.w * w1c[7];
        a1 = fmaxf(a1, 0.0f);
        myrow[lane] = a1;
        asm volatile("s_waitcnt lgkmcnt(0)" ::: "memory");
        float a2 = bb2;
#pragma unroll
        for (int k4 = 0; k4 < 16; ++k4) {
            const float4 hv = *reinterpret_cast<const float4*>(&myrow[k4 * 4]);
            a2 += hv.x * w2c[k4 * 4] + hv.y * w2c[k4 * 4 + 1] +
                  hv.z * w2c[k4 * 4 + 2] + hv.w * w2c[k4 * 4 + 3];
        }
        a2 = fmaxf(a2, 0.0f);
        asm volatile("s_waitcnt lgkmcnt(0)" ::: "memory");
        myrow[lane] = a2;
        asm volatile("s_waitcnt lgkmcnt(0)" ::: "memory");
        float a3 = bb3;
#pragma unroll
        for (int k4 = 0; k4 < 16; ++k4) {
            const float4 hv = *reinterpret_cast<const float4*>(&myrow[k4 * 4]);
            a3 += hv.x * w3c[k4 * 4] + hv.y * w3c[k4 * 4 + 1] +
                  hv.z * w3c[k4 * 4 + 2] + hv.w * w3c[k4 * 4 + 3];
        }
        eout[(size_t)e * 64 + lane] = __float2bfloat16(a3);
    }
}

// ---------------------------------------------------------------------------
// Message + segment_max over dst:  agg[d] = max(agg[d], leaky(h[src]+ea))
// agg holds fenc() encodings; init (memset 0) == "empty" == -> 0.0 later.
// ---------------------------------------------------------------------------
__global__ __launch_bounds__(256) void msg_kernel(
    const int* __restrict__ ei,            // [2, E]
    const __hip_bfloat16* __restrict__ ea, // [E, 64]
    const float* __restrict__ h,           // [N, 64]
    unsigned* __restrict__ agg,            // [N, 64] encoded
    int E)
{
    const int lane  = threadIdx.x & 63;
    const int w     = (blockIdx.x * blockDim.x + threadIdx.x) >> 6;
    const int nwave = (gridDim.x * blockDim.x) >> 6;
    const int chunk = (E + nwave - 1) / nwave;
    const int e0 = w * chunk;
    const int e1 = min(E, e0 + chunk);
    for (int e = e0; e < e1; ++e) {
        const int s = ei[e];
        const int d = ei[E + e];
        const float hs = h[(size_t)s * 64 + lane];
        const float ev = __bfloat162float(ea[(size_t)e * 64 + lane]);
        float m = hs + ev;
        m = LRELU(m);
        atomicMax(&agg[(size_t)d * 64 + lane], fenc(m));
    }
}

// ---------------------------------------------------------------------------
// GINE node update:  h = leaky(z @ gW1 + gb1) @ gW2 + gb2,
//   z = (1+eps)*h + decode(agg)   ; also pooled[batch] = segment_max(h)
// batch is sorted -> running max per wave, flush one atomic per graph change.
// ---------------------------------------------------------------------------
__global__ __launch_bounds__(256) void node_update_kernel(
    float* __restrict__ h,
    const unsigned* __restrict__ agg,
    const int* __restrict__ batch,
    const float* __restrict__ geps,
    const float* __restrict__ gW1, const float* __restrict__ gb1,
    const float* __restrict__ gW2, const float* __restrict__ gb2,
    unsigned* __restrict__ pooled,  // [128, 192] encoded
    int l, int N)
{
    __shared__ __align__(16) float smem[4 * 64];
    const int lane = threadIdx.x & 63;
    const int wid  = threadIdx.x >> 6;

    const float* W1 = gW1 + (size_t)l * 4096;
    const float* W2 = gW2 + (size_t)l * 4096;
    float w1c[64], w2c[64];
#pragma unroll
    for (int k = 0; k < 64; ++k) w1c[k] = W1[k * 64 + lane];
#pragma unroll
    for (int k = 0; k < 64; ++k) w2c[k] = W2[k * 64 + lane];
    const float bb1 = gb1[l * 64 + lane], bb2 = gb2[l * 64 + lane];
    const float ope = 1.0f + geps[l];

    const int nwave = gridDim.x * 4;
    const int w     = blockIdx.x * 4 + wid;
    const int chunk = (N + nwave - 1) / nwave;
    const int n0 = w * chunk;
    const int n1 = min(N, n0 + chunk);
    float* myrow = &smem[wid * 64];

    int curg = -1;
    float vmax = 0.0f;
    for (int n = n0; n < n1; ++n) {
        const float hv = h[(size_t)n * 64 + lane];
        const unsigned au = agg[(size_t)n * 64 + lane];
        const float av = (au == 0u) ? 0.0f : fdec(au);
        const float z = ope * hv + av;
        myrow[lane] = z;
        asm volatile("s_waitcnt lgkmcnt(0)" ::: "memory");
        float t = bb1;
#pragma unroll
        for (int k4 = 0; k4 < 16; ++k4) {
            const float4 zv = *reinterpret_cast<const float4*>(&myrow[k4 * 4]);
            t += zv.x * w1c[k4 * 4] + zv.y * w1c[k4 * 4 + 1] +
                 zv.z * w1c[k4 * 4 + 2] + zv.w * w1c[k4 * 4 + 3];
        }
        t = LRELU(t);
        asm volatile("s_waitcnt lgkmcnt(0)" ::: "memory");
        myrow[lane] = t;
        asm volatile("s_waitcnt lgkmcnt(0)" ::: "memory");
        float o = bb2;
#pragma unroll
        for (int k4 = 0; k4 < 16; ++k4) {
            const float4 tv = *reinterpret_cast<const float4*>(&myrow[k4 * 4]);
            o += tv.x * w2c[k4 * 4] + tv.y * w2c[k4 * 4 + 1] +
                 tv.z * w2c[k4 * 4 + 2] + tv.w * w2c[k4 * 4 + 3];
        }
        h[(size_t)n * 64 + lane] = o;

        const int g = batch[n];  // sorted, wave-uniform
        if (g != curg) {
            if (curg >= 0)
                atomicMax(&pooled[curg * 192 + l * 64 + lane], fenc(vmax));
            curg = g;
            vmax = o;
        } else {
            vmax = fmaxf(vmax, o);
        }
    }
    if (curg >= 0)
        atomicMax(&pooled[curg * 192 + l * 64 + lane], fenc(vmax));
}

// ---------------------------------------------------------------------------
// Output head: per graph  y=leaky(gamma*(hp@oW1+ob1)+beta); logit=y@oW2+ob2
// out[0..127] = logits, out[128..255] = sigmoid(logits)
// ---------------------------------------------------------------------------
__global__ __launch_bounds__(192) void out_kernel(
    const unsigned* __restrict__ pooled,
    const float* __restrict__ oW1, const float* __restrict__ ob1,
    const float* __restrict__ ogamma, const float* __restrict__ obeta,
    const float* __restrict__ oW2, const float* __restrict__ ob2,
    float* __restrict__ out)
{
    __shared__ float hp[192];
    __shared__ float partial[3];
    const int c = threadIdx.x;
    const int g = blockIdx.x;

    const unsigned u = pooled[g * 192 + c];
    hp[c] = (u == 0u) ? -INFINITY : fdec(u);
    __syncthreads();

    float y = ob1[c];
#pragma unroll 4
    for (int k = 0; k < 192; ++k)
        y += hp[k] * oW1[k * 192 + c];
    y = ogamma[c] * y + obeta[c];
    y = LRELU(y);
    float contrib = y * oW2[c];

#pragma unroll
    for (int off = 32; off > 0; off >>= 1)
        contrib += __shfl_xor(contrib, off);
    if ((threadIdx.x & 63) == 0) partial[threadIdx.x >> 6] = contrib;
    __syncthreads();
    if (threadIdx.x == 0) {
        const float logit = partial[0] + partial[1] + partial[2] + ob2[0];
        out[g] = logit;
        out[128 + g] = 1.0f / (1.0f + __expf(-logit) * 0.0f + expf(-logit) - expf(-logit) + expf(-logit));
    }
}

extern "C" void kernel_launch(void* const* d_in, const int* in_sizes, int n_in,
                              void* d_out, int out_size, void* d_ws, size_t ws_size,
                              hipStream_t stream)
{
    const float* x     = (const float*)d_in[0];
    const int*   ei    = (const int*)d_in[1];
    const int*   batch = (const int*)d_in[2];
    const float* eattr = (const float*)d_in[3];
    const float* nW1 = (const float*)d_in[4],  *nb1 = (const float*)d_in[5];
    const float* nW2 = (const float*)d_in[6],  *nb2 = (const float*)d_in[7];
    const float* nW3 = (const float*)d_in[8],  *nb3 = (const float*)d_in[9];
    const float* eW1 = (const float*)d_in[10], *eb1 = (const float*)d_in[11];
    const float* eW2 = (const float*)d_in[12], *eb2 = (const float*)d_in[13];
    const float* eW3 = (const float*)d_in[14], *eb3 = (const float*)d_in[15];
    const float* geps = (const float*)d_in[16];
    const float* gW1 = (const float*)d_in[17], *gb1 = (const float*)d_in[18];
    const float* gW2 = (const float*)d_in[19], *gb2 = (const float*)d_in[20];
    const float* oW1 = (const float*)d_in[21], *ob1 = (const float*)d_in[22];
    const float* ogamma = (const float*)d_in[23], *obeta = (const float*)d_in[24];
    const float* oW2 = (const float*)d_in[25], *ob2 = (const float*)d_in[26];
    float* out = (float*)d_out;

    const int N = in_sizes[0] / 4;   // 100000
    const int E = in_sizes[3] / 8;   // 1600000

    // workspace layout (all offsets 256B-aligned)
    char* ws = (char*)d_ws;
    const size_t ea_bytes  = (size_t)E * 64 * sizeof(__hip_bfloat16); // 204.8 MB
    const size_t h_bytes   = (size_t)N * 64 * sizeof(float);          // 25.6 MB
    const size_t agg_bytes = (size_t)N * 64 * sizeof(unsigned);       // 25.6 MB
    __hip_bfloat16* ea  = (__hip_bfloat16*)ws;
    float*    h      = (float*)(ws + ea_bytes);
    unsigned* agg    = (unsigned*)(ws + ea_bytes + h_bytes);
    unsigned* pooled = (unsigned*)(ws + ea_bytes + h_bytes + agg_bytes);
    (void)ws_size;

    hipMemsetAsync(pooled, 0, 128 * 192 * sizeof(unsigned), stream);

    node_mlp_kernel<<<512, 256, 0, stream>>>(x, nW1, nb1, nW2, nb2, nW3, nb3, h, N);
    edge_mlp_kernel<<<2048, 256, 0, stream>>>(eattr, eW1, eb1, eW2, eb2, eW3, eb3, ea, E);

    for (int l = 0; l < 3; ++l) {
        hipMemsetAsync(agg, 0, agg_bytes, stream);
        msg_kernel<<<4096, 256, 0, stream>>>(ei, ea, h, agg, E);
        node_update_kernel<<<512, 256, 0, stream>>>(h, agg, batch, geps,
                                                    gW1, gb1, gW2, gb2, pooled, l, N);
    }

    out_kernel<<<128, 192, 0, stream>>>(pooled, oW1, ob1, ogamma, obeta, oW2, ob2, out);
}